// Round 15
// baseline (412.858 us; speedup 1.0000x reference)
//
#include <hip/hip_runtime.h>
#include <stdint.h>
#include <string.h>
#include <cmath>

// SpikingYOLO round 33: R31 base (302.7us bank) + conv engines converted to
// register-resident, barrier-free, LDS-free per-wave pipelines ON THE DENSE
// LAYOUT (R23's structure re-tried in the corrected regime per rule #23 —
// its 204us failure was measured with strided loads, pre-R24). Per phase a
// wave issues 8 dense A-frag loads + 6 B loads for phase p+1, VMCNT(14),
// 24 MFMAs. No LDS, no s_barrier, fully independent waves. Lane-level load
// addresses reproduce the LDS round-trip bytes exactly and MFMA order is
// unchanged -> numerics BIT-IDENTICAL to R31 (absmax 0.006835938).
// conv1/lif_s2_t/lif_mean1/det/zpads/wtrans byte-identical to R31.

#define BB 4
#define TT 10

typedef short bf16x8 __attribute__((ext_vector_type(8)));
typedef float f32x4  __attribute__((ext_vector_type(4)));

#define MFMA16(a, b, c) __builtin_amdgcn_mfma_f32_16x16x32_bf16((a), (b), (c), 0, 0, 0)

// s1p2: [40][129 rows][parity 2][cih 2][col2 66][cil 32] bf16
//   row stride 8448 elems, parity 4224, cih 2112; plane 1,089,792 elems.
// s2p3: [40][65][parity 2][cih 4][col2 34][cil 32] bf16
//   row stride 8704 elems, parity 4352, cih 1088; plane 565,760 elems.

__global__ __launch_bounds__(256) void zpad1v(uint32_t* __restrict__ buf) {
    uint32_t* p = buf + (size_t)blockIdx.x * 544896u;
    for (int i = threadIdx.x; i < 8320; i += 256) {
        if (i < 4224) p[i] = 0u;
        else {
            int j = i - 4224;
            int row = 1 + (j >> 5), cih = (j >> 4) & 1, e = j & 15;
            p[row * 4224 + 2112 + cih * 1056 + e] = 0u;
        }
    }
}

__global__ __launch_bounds__(256) void zpad3v(uint32_t* __restrict__ buf) {
    uint32_t* p = buf + (size_t)blockIdx.x * 282880u;
    for (int i = threadIdx.x; i < 8448; i += 256) {
        if (i < 4352) p[i] = 0u;
        else {
            int j = i - 4352;
            int row = 1 + (j >> 6), cih = (j >> 4) & 3, e = j & 15;
            p[row * 4352 + 2176 + cih * 544 + e] = 0u;
        }
    }
}

// ---------------------------------------------------------------- conv1+LIF
// Byte-identical to R31 (LDS-coalesced spike drain).
__global__ __launch_bounds__(256) void conv1_lif(
    const float* __restrict__ x,    // [4,2,128,128,10]
    const float* __restrict__ w1,   // [64,2,3,3]
    const float* __restrict__ b1,   // [64]
    unsigned short* __restrict__ s1p2,
    float alpha, float beta)
{
    __shared__ float xs[2][3][10][10];   // [ci][kh][wi][t]
    __shared__ float wsh[18][64];        // [tap][co]
    __shared__ uint32_t spk[40][68];
    const int tid = threadIdx.x;
    const int b = blockIdx.z, h = blockIdx.y, w0 = blockIdx.x * 8;

    for (int i = tid; i < 1152; i += 256) {
        int co = i & 63, tap = i >> 6;
        wsh[tap][co] = w1[co * 18 + tap];
    }
    for (int i = tid; i < 600; i += 256) {
        int t = i % 10; int rest = i / 10;
        int wi = rest % 10; rest /= 10;
        int kh = rest % 3; int ci = rest / 3;
        int hh = h - 1 + kh, ww = w0 - 1 + wi;
        float v = 0.f;
        if (hh >= 0 && hh < 128 && ww >= 0 && ww < 128)
            v = x[(((b * 2 + ci) * 128 + hh) * 128 + ww) * 10 + t];
        xs[ci][kh][wi][t] = v;
    }
    __syncthreads();

    const int px  = tid & 7;
    const int cog = (tid >> 3) * 2;
    float acc[2][10];
#pragma unroll
    for (int c = 0; c < 2; ++c)
#pragma unroll
        for (int t = 0; t < 10; ++t) acc[c][t] = 0.f;

#pragma unroll
    for (int tap = 0; tap < 18; ++tap) {
        const int ci = tap / 9, kh = (tap % 9) / 3, kw = tap % 3;
        float2 wv = *(const float2*)&wsh[tap][cog];
#pragma unroll
        for (int t = 0; t < 10; ++t) {
            float xv = xs[ci][kh][px + kw][t];
            acc[0][t] = __fmaf_rn(wv.x, xv, acc[0][t]);
            acc[1][t] = __fmaf_rn(wv.y, xv, acc[1][t]);
        }
    }
    const int pr    = px & 1;
    const int col2l = px >> 1;
    const int comb0 = pr * 2 + (cog >> 5);
    const int ipos  = col2l * 16 + ((cog & 31) >> 1);
    const float bv0 = b1[cog], bv1 = b1[cog + 1];
    float syn0 = 0.f, mem0 = 0.f, syn1 = 0.f, mem1 = 0.f;
#pragma unroll
    for (int t = 0; t < 10; ++t) {
        float cur0 = __fadd_rn(acc[0][t], bv0);
        syn0 = __fadd_rn(__fmul_rn(beta, syn0), cur0);
        mem0 = __fadd_rn(__fmul_rn(alpha, mem0), syn0);
        bool s0 = (mem0 >= 1.0f);
        mem0 = __fsub_rn(mem0, s0 ? 1.0f : 0.0f);
        float cur1 = __fadd_rn(acc[1][t], bv1);
        syn1 = __fadd_rn(__fmul_rn(beta, syn1), cur1);
        mem1 = __fadd_rn(__fmul_rn(alpha, mem1), syn1);
        bool s1 = (mem1 >= 1.0f);
        mem1 = __fsub_rn(mem1, s1 ? 1.0f : 0.0f);
        spk[t * 4 + comb0][ipos] =
            (s0 ? 0x3F80u : 0u) | ((s1 ? 0x3F80u : 0u) << 16);
    }
    __syncthreads();

    uint32_t* sg = (uint32_t*)s1p2;
    const int e = tid & 63;
#pragma unroll
    for (int k = 0; k < 10; ++k) {
        const int combo = k * 4 + (tid >> 6);       // 0..39
        const int t  = combo >> 2;
        const int pp = (combo >> 1) & 1;
        const int ch = combo & 1;
        const uint32_t ga = (uint32_t)(t * BB + b) * 544896u
            + ((uint32_t)((h + 1) * 8448 + pp * 4224 + ch * 2112
                          + ((w0 >> 1) + pp) * 32) >> 1) + e;
        sg[ga] = spk[combo][e];
    }
}

// --------- w2 -> 3-term bf16 split (unchanged from R20..R31).
__global__ __launch_bounds__(256) void wtrans2c(
    const float* __restrict__ w2, unsigned short* __restrict__ wtb)
{
    int i = blockIdx.x * 256 + threadIdx.x;
    if (i >= 73728) return;                  // 128*64*9
    int co  = i / 576;
    int rem = i - co * 576;
    int ci  = rem / 9;
    int tap = rem - ci * 9;
    float w = w2[i];                         // [co][ci][kh][kw]
    uint32_t uw  = __float_as_uint(w);
    uint32_t h16 = (uw + 0x7FFFu + ((uw >> 16) & 1u)) >> 16;   // RNE bf16
    float hf = __uint_as_float(h16 << 16);
    float r1 = w - hf;
    uint32_t ur1 = __float_as_uint(r1);
    uint32_t m16 = (ur1 + 0x7FFFu + ((ur1 >> 16) & 1u)) >> 16;
    float mf = __uint_as_float(m16 << 16);
    float r2 = r1 - mf;
    uint32_t ur2 = __float_as_uint(r2);
    uint32_t l16 = (ur2 + 0x7FFFu + ((ur2 >> 16) & 1u)) >> 16;

    int cobi = co >> 6, coL = co & 63;
    int wid = coL >> 4, l15 = coL & 15;
    int c = ci >> 5, r5 = ci & 31;
    int g = r5 >> 3, e = r5 & 7;
    size_t base = (size_t)(cobi * 27 + tap * 3) * 4096
                + (size_t)(((wid * 2 + c) * 64 + (g * 16 + l15)) * 8 + e);
    wtb[base]        = (unsigned short)h16;
    wtb[base + 4096] = (unsigned short)m16;
    wtb[base + 8192] = (unsigned short)l16;
}

// --------- w3 -> 3-term bf16 split (unchanged from R20..R31).
__global__ __launch_bounds__(256) void wtrans3c(
    const float* __restrict__ w3, unsigned short* __restrict__ wtb)
{
    int i = blockIdx.x * 256 + threadIdx.x;
    if (i >= 294912) return;                 // 256*128*9
    int co  = i / 1152;
    int rem = i - co * 1152;
    int ci  = rem / 9;
    int tap = rem - ci * 9;
    float w = w3[i];                         // [co][ci][kh][kw]
    uint32_t uw  = __float_as_uint(w);
    uint32_t h16 = (uw + 0x7FFFu + ((uw >> 16) & 1u)) >> 16;
    float hf = __uint_as_float(h16 << 16);
    float r1 = w - hf;
    uint32_t ur1 = __float_as_uint(r1);
    uint32_t m16 = (ur1 + 0x7FFFu + ((ur1 >> 16) & 1u)) >> 16;
    float mf = __uint_as_float(m16 << 16);
    float r2 = r1 - mf;
    uint32_t ur2 = __float_as_uint(r2);
    uint32_t l16 = (ur2 + 0x7FFFu + ((ur2 >> 16) & 1u)) >> 16;

    int cobi = co >> 6, coL = co & 63;
    int wq = coL >> 4, l15 = coL & 15;
    int cc = ci >> 5, r5 = ci & 31;
    int g = r5 >> 3, e = r5 & 7;
    size_t base = (size_t)(cobi * 27 + tap * 3) * 8192
                + (size_t)(((wq * 4 + cc) * 64 + (g * 16 + l15)) * 8 + e);
    wtb[base]         = (unsigned short)h16;
    wtb[base + 8192]  = (unsigned short)m16;
    wtb[base + 16384] = (unsigned short)l16;
}

#define VMCNT(n) do { __builtin_amdgcn_sched_barrier(0); \
    asm volatile("s_waitcnt vmcnt(" #n ")" ::: "memory"); \
    __builtin_amdgcn_sched_barrier(0); } while (0)
#define SB() __builtin_amdgcn_sched_barrier(0)
#define PRIO1() __builtin_amdgcn_s_setprio(1)
#define PRIO0() __builtin_amdgcn_s_setprio(0)

// ------------------- L2 conv via MFMA, register-resident barrier-free.
// Block: 4 independent waves; wave owns co-quarter [cobi*64+w*16,+16) x
// 64 px (1 row). Phase = tap: issue 8 dense A-frag loads + 6 B loads for
// tap+1 (alternate reg buffers), VMCNT(14), 24-MFMA cluster. No LDS, no
// barrier. Fragment bytes and MFMA order identical to R31's LDS path.
__global__ __launch_bounds__(256) void conv2_mfma(
    const unsigned short* __restrict__ s1p2,
    const unsigned short* __restrict__ wtb,   // [2][27][4096]
    float* __restrict__ p2)                   // [40][4096][128]
{
    const int tid  = threadIdx.x;
    const int lane = tid & 63, w = tid >> 6;   // w = 0..3
    const int r = lane & 15, g = lane >> 4;
    const int f = blockIdx.z;
    const int cobi = blockIdx.y;               // 0,1
    const int hb = blockIdx.x;                 // output row 0..63

    const unsigned short* fb = s1p2 + (uint32_t)f * 1089792u;
    const unsigned short* wB = wtb + (uint32_t)cobi * (27u * 4096u)
                             + (uint32_t)w * 1024u + (uint32_t)lane * 8u;
    const uint32_t lfo = (uint32_t)(r * 32 + g * 8);   // in-frag lane offset

    f32x4 acc[4];
#pragma unroll
    for (int mt = 0; mt < 4; ++mt) acc[mt] = (f32x4){0.f, 0.f, 0.f, 0.f};
    bf16x8 aA[8], aB[8], bA[6], bB[6];

#define LOADA2(tap_, DST) do { \
    const int kh_ = (tap_) / 3, kw_ = (tap_) % 3; \
    const int p_ = (kw_ == 1) ? 0 : 1; \
    const int cf_ = (kw_ == 2) ? 1 : 0; \
    _Pragma("unroll") \
    for (int q_ = 0; q_ < 8; ++q_) { \
        const int mt_ = q_ >> 1, c_ = q_ & 1; \
        DST[q_] = *(const bf16x8*)(fb + (uint32_t)(2 * hb + kh_) * 8448u \
            + (uint32_t)p_ * 4224u + (uint32_t)c_ * 2112u \
            + (uint32_t)(mt_ * 16 + cf_) * 32u + lfo); \
    } } while (0)

#define LOADB2(tap_, DST) do { _Pragma("unroll") \
    for (int t_ = 0; t_ < 3; ++t_) { _Pragma("unroll") \
        for (int c_ = 0; c_ < 2; ++c_) \
            DST[t_ * 2 + c_] = *(const bf16x8*)(wB + (uint32_t)((tap_) * 3 + t_) * 4096u + c_ * 512u); \
    } } while (0)

#define COMP2(AU, BU) do { _Pragma("unroll") \
    for (int t_ = 0; t_ < 3; ++t_) { _Pragma("unroll") \
        for (int c_ = 0; c_ < 2; ++c_) { \
            bf16x8 b_ = BU[t_ * 2 + c_]; \
            acc[0] = MFMA16(b_, AU[0 + c_], acc[0]); \
            acc[1] = MFMA16(b_, AU[2 + c_], acc[1]); \
            acc[2] = MFMA16(b_, AU[4 + c_], acc[2]); \
            acc[3] = MFMA16(b_, AU[6 + c_], acc[3]); \
        } } } while (0)

#define PH2(tap_, AU, BU, AN, BN) do { \
    SB(); LOADA2((tap_) + 1, AN); LOADB2((tap_) + 1, BN); SB(); \
    VMCNT(14); \
    PRIO1(); COMP2(AU, BU); PRIO0(); SB(); \
} while (0)

    LOADA2(0, aA); LOADB2(0, bA);
    PH2(0, aA, bA, aB, bB); PH2(1, aB, bB, aA, bA);
    PH2(2, aA, bA, aB, bB); PH2(3, aB, bB, aA, bA);
    PH2(4, aA, bA, aB, bB); PH2(5, aB, bB, aA, bA);
    PH2(6, aA, bA, aB, bB); PH2(7, aB, bB, aA, bA);
    // tap 8 tail (loaded into aA/bA by PH2(7))
    SB(); VMCNT(0);
    PRIO1(); COMP2(aA, bA); PRIO0();

#pragma unroll
    for (int mt = 0; mt < 4; ++mt)
        *(f32x4*)&p2[((uint32_t)f * 4096u + hb * 64 + mt * 16 + r) * 128u
                     + cobi * 64 + w * 16 + g * 4] = acc[mt];
#undef LOADA2
#undef LOADB2
#undef COMP2
#undef PH2
}

// ---------------------- LIF layer 2: MFMA partial -> bf16 spikes (s2p3).
// Byte-identical to R31.
__global__ __launch_bounds__(256) void lif_s2_t(
    const float* __restrict__ pa, const float* __restrict__ bias,
    unsigned short* __restrict__ s2p3, float alpha, float beta)
{
    const int tid = threadIdx.x;
    const int b   = blockIdx.z;
    const int px  = blockIdx.x * 8 + (tid >> 5);
    const int co0 = (tid & 31) * 4;
    const int h = px >> 6, w = px & 63;
    float4 bv = *(const float4*)&bias[co0];
    const float bva[4] = {bv.x, bv.y, bv.z, bv.w};
    float syn[4] = {0.f,0.f,0.f,0.f}, mem[4] = {0.f,0.f,0.f,0.f};
    const int pr = w & 1;
    const int col2 = (w + pr) >> 1;
    unsigned short* sp = s2p3 + (uint32_t)(h + 1) * 8704u + pr * 4352u
                       + (co0 >> 5) * 1088u + col2 * 32u + (co0 & 31);
    for (int t = 0; t < TT; ++t) {
        const int f = t * BB + b;
        const uint32_t idx = ((uint32_t)f * 4096u + px) * 128u + co0;
        float4 A = *(const float4*)&pa[idx];
        const float va[4] = {A.x, A.y, A.z, A.w};
        uint32_t pk[2] = {0u, 0u};
#pragma unroll
        for (int j = 0; j < 4; ++j) {
            float c = __fadd_rn(va[j], bva[j]);
            syn[j] = __fadd_rn(__fmul_rn(beta, syn[j]), c);
            mem[j] = __fadd_rn(__fmul_rn(alpha, mem[j]), syn[j]);
            bool sc = (mem[j] >= 1.0f);
            mem[j] = __fsub_rn(mem[j], sc ? 1.0f : 0.0f);
            pk[j >> 1] |= (sc ? 0x3F80u : 0u) << ((j & 1) * 16);
        }
        *(uint2*)(sp + (uint32_t)f * 565760u) = make_uint2(pk[0], pk[1]);
    }
}

// ------------------- L3 conv via MFMA, register-resident barrier-free.
// Block: 4 independent waves; wave owns co-quarter x 64 px (2 rows).
// Phase = half-tap: 8 dense A loads + 6 B loads for next tile, VMCNT(14),
// 24 MFMAs. 18 phases. Fragment bytes and MFMA order identical to R31.
__global__ __launch_bounds__(256) void conv3_mfma3(
    const unsigned short* __restrict__ s2p3,
    const unsigned short* __restrict__ wtb,   // [4][27][8192]
    float* __restrict__ p3)                   // [40][256][32][32]
{
    const int tid  = threadIdx.x;
    const int lane = tid & 63, w = tid >> 6;   // w = 0..3
    const int r = lane & 15, g = lane >> 4;
    const int f = blockIdx.z;
    const int cobi = blockIdx.y;               // 0..3
    const int h0 = blockIdx.x * 2;

    const unsigned short* fb = s2p3 + (uint32_t)f * 565760u;
    const unsigned short* wB = wtb + (uint32_t)cobi * (27u * 8192u)
                             + (uint32_t)w * 2048u + (uint32_t)lane * 8u;
    const uint32_t lfo = (uint32_t)(r * 32 + g * 8);

    f32x4 acc[4];
#pragma unroll
    for (int mt = 0; mt < 4; ++mt) acc[mt] = (f32x4){0.f, 0.f, 0.f, 0.f};
    bf16x8 aA[8], aB[8], bA[6], bB[6];

#define LOADA3(tap_, half_, DST) do { \
    const int kh_ = (tap_) / 3, kw_ = (tap_) % 3; \
    const int p_ = (kw_ == 1) ? 0 : 1; \
    const int cf_ = (kw_ == 2) ? 1 : 0; \
    _Pragma("unroll") \
    for (int q_ = 0; q_ < 8; ++q_) { \
        const int mt_ = q_ >> 1, j_ = q_ & 1; \
        DST[q_] = *(const bf16x8*)(fb \
            + (uint32_t)(2 * (h0 + (mt_ >> 1)) + kh_) * 8704u \
            + (uint32_t)p_ * 4352u + (uint32_t)((half_) * 2 + j_) * 1088u \
            + (uint32_t)((mt_ & 1) * 16 + cf_) * 32u + lfo); \
    } } while (0)

#define LOADB3(tap_, half_, DST) do { _Pragma("unroll") \
    for (int t_ = 0; t_ < 3; ++t_) { _Pragma("unroll") \
        for (int j_ = 0; j_ < 2; ++j_) \
            DST[t_ * 2 + j_] = *(const bf16x8*)(wB + (uint32_t)((tap_) * 3 + t_) * 8192u \
                + (uint32_t)((half_) * 2 + j_) * 512u); \
    } } while (0)

#define COMP3(AU, BU) do { _Pragma("unroll") \
    for (int t_ = 0; t_ < 3; ++t_) { _Pragma("unroll") \
        for (int j_ = 0; j_ < 2; ++j_) { \
            bf16x8 b_ = BU[t_ * 2 + j_]; \
            acc[0] = MFMA16(AU[0 + j_], b_, acc[0]); \
            acc[1] = MFMA16(AU[2 + j_], b_, acc[1]); \
            acc[2] = MFMA16(AU[4 + j_], b_, acc[2]); \
            acc[3] = MFMA16(AU[6 + j_], b_, acc[3]); \
        } } } while (0)

#define PH3(ntap_, nhalf_, AU, BU, AN, BN) do { \
    SB(); LOADA3(ntap_, nhalf_, AN); LOADB3(ntap_, nhalf_, BN); SB(); \
    VMCNT(14); \
    PRIO1(); COMP3(AU, BU); PRIO0(); SB(); \
} while (0)

    LOADA3(0, 0, aA); LOADB3(0, 0, bA);
    PH3(0, 1, aA, bA, aB, bB); PH3(1, 0, aB, bB, aA, bA);
    PH3(1, 1, aA, bA, aB, bB); PH3(2, 0, aB, bB, aA, bA);
    PH3(2, 1, aA, bA, aB, bB); PH3(3, 0, aB, bB, aA, bA);
    PH3(3, 1, aA, bA, aB, bB); PH3(4, 0, aB, bB, aA, bA);
    PH3(4, 1, aA, bA, aB, bB); PH3(5, 0, aB, bB, aA, bA);
    PH3(5, 1, aA, bA, aB, bB); PH3(6, 0, aB, bB, aA, bA);
    PH3(6, 1, aA, bA, aB, bB); PH3(7, 0, aB, bB, aA, bA);
    PH3(7, 1, aA, bA, aB, bB); PH3(8, 0, aB, bB, aA, bA);
    PH3(8, 1, aA, bA, aB, bB);
    // tile 17 tail (tap 8, half 1; loaded into aB/bB by the last PH3)
    SB(); VMCNT(0);
    PRIO1(); COMP3(aB, bB); PRIO0();

#pragma unroll
    for (int mt = 0; mt < 4; ++mt) {
        const int hh = h0 + (mt >> 1);
        const int wc = (mt & 1) * 16 + g * 4;
        *(f32x4*)&p3[((uint32_t)(f * 256 + cobi * 64 + w * 16 + r) * 32u + hh) * 32u + wc] = acc[mt];
    }
#undef LOADA3
#undef LOADB3
#undef COMP3
#undef PH3
}

// ---------------------- LIF + time-mean from the single conv3 buffer
__global__ __launch_bounds__(256) void lif_mean1(
    const float* __restrict__ p3, const float* __restrict__ bias,
    float* __restrict__ pooled, float alpha, float beta)
{
    const int px = (blockIdx.x * 256 + threadIdx.x) * 4;
    const int co = blockIdx.y;
    const int b  = blockIdx.z;
    const float bv = bias[co];
    float syn[4] = {0.f,0.f,0.f,0.f}, mem[4] = {0.f,0.f,0.f,0.f};
    float sum[4] = {0.f,0.f,0.f,0.f};
    for (int t = 0; t < TT; ++t) {
        const int idx = ((t * BB + b) * 256 + co) * 1024 + px;
        float4 a = *(const float4*)&p3[idx];
        const float va[4] = {a.x, a.y, a.z, a.w};
#pragma unroll
        for (int j = 0; j < 4; ++j) {
            float cu = __fadd_rn(va[j], bv);
            syn[j] = __fadd_rn(__fmul_rn(beta, syn[j]), cu);
            mem[j] = __fadd_rn(__fmul_rn(alpha, mem[j]), syn[j]);
            bool sc = (mem[j] >= 1.0f);
            float sp = sc ? 1.0f : 0.0f;
            mem[j] = __fsub_rn(mem[j], sp);
            sum[j] = __fadd_rn(sum[j], sp);
        }
    }
    *(float4*)&pooled[(b * 256 + co) * 1024 + px] =
        make_float4(sum[0] / 10.0f, sum[1] / 10.0f, sum[2] / 10.0f, sum[3] / 10.0f);
}

// ------------------------------------------------------------------ det 1x1
__global__ __launch_bounds__(256) void det_conv(
    const float* __restrict__ pooled, // [4,256,1024]
    const float* __restrict__ wd,     // [255,256]
    const float* __restrict__ bd,     // [255]
    float* __restrict__ out)          // [4,255,1024]
{
    __shared__ float wtl[16][64];
    __shared__ float ps[16][64];
    const int tid = threadIdx.x;
    const int b = blockIdx.z;
    const int o_base = blockIdx.y * 64;
    const int px_base = blockIdx.x * 64;
    const int o_off = (tid >> 4) * 4;
    const int px_off = (tid & 15) * 4;
    float acc[4][4];
#pragma unroll
    for (int c = 0; c < 4; ++c) {
        int o = o_base + o_off + c;
        float bv = (o < 255) ? bd[o] : 0.f;
#pragma unroll
        for (int j = 0; j < 4; ++j) acc[c][j] = bv;
    }
    for (int cc = 0; cc < 16; ++cc) {
        for (int k = tid; k < 1024; k += 256) {
            int o = k & 63, ci = k >> 6;
            wtl[ci][o] = (o_base + o < 255) ? wd[(o_base + o) * 256 + cc * 16 + ci] : 0.f;
            ps[ci][o] = pooled[(b * 256 + cc * 16 + ci) * 1024 + px_base + o];
        }
        __syncthreads();
#pragma unroll
        for (int ci = 0; ci < 16; ++ci) {
            float4 wv = *(const float4*)&wtl[ci][o_off];
            float4 sv = *(const float4*)&ps[ci][px_off];
            acc[0][0] += wv.x * sv.x; acc[0][1] += wv.x * sv.y;
            acc[0][2] += wv.x * sv.z; acc[0][3] += wv.x * sv.w;
            acc[1][0] += wv.y * sv.x; acc[1][1] += wv.y * sv.y;
            acc[1][2] += wv.y * sv.z; acc[1][3] += wv.y * sv.w;
            acc[2][0] += wv.z * sv.x; acc[2][1] += wv.z * sv.y;
            acc[2][2] += wv.z * sv.z; acc[2][3] += wv.z * sv.w;
            acc[3][0] += wv.w * sv.x; acc[3][1] += wv.w * sv.y;
            acc[3][2] += wv.w * sv.z; acc[3][3] += wv.w * sv.w;
        }
        __syncthreads();
    }
#pragma unroll
    for (int c = 0; c < 4; ++c) {
        int o = o_base + o_off + c;
        if (o < 255)
            *(float4*)&out[(b * 255 + o) * 1024 + px_base + px_off] =
                make_float4(acc[c][0], acc[c][1], acc[c][2], acc[c][3]);
    }
}

extern "C" void kernel_launch(void* const* d_in, const int* in_sizes, int n_in,
                              void* d_out, int out_size, void* d_ws, size_t ws_size,
                              hipStream_t stream) {
    const float* x  = (const float*)d_in[0];
    const float* w1 = (const float*)d_in[1];
    const float* b1 = (const float*)d_in[2];
    const float* w2 = (const float*)d_in[3];
    const float* b2 = (const float*)d_in[4];
    const float* w3 = (const float*)d_in[5];
    const float* b3 = (const float*)d_in[6];
    const float* wd = (const float*)d_in[7];
    const float* bd = (const float*)d_in[8];
    float* out = (float*)d_out;

    // ws layout with aliasing (lifetimes; ~218.5 MB), identical to R29/R31:
    //   s1p2 u16 [40][1,089,792]   @ 256          (87,183,360)  conv1 -> conv2
    //   p3   f32 [40*256*1024]     @ 256          (41,943,040)  conv3 -> lif_mean1 (overlays s1p2)
    //   p2   f32 [40][4096][128]   @ 87,183,616   (83,886,080)  conv2 -> lif_s2_t
    //   pooled f32                 @ 87,183,616   (4,194,304)   lif_mean1 -> det (overlays p2)
    //   s2p3 u16 [40][565,760]     @ 171,069,696  (45,260,800)  lif_s2_t -> conv3
    //   wt2b u16 [2][27][4096]     @ 216,330,496  (442,368)
    //   wt3b u16 [4][27][8192]     @ 216,772,864  (1,769,472)   end 218,542,336
    uint8_t* wsb = (uint8_t*)d_ws;
    unsigned short* s1p2 = (unsigned short*)(wsb + 256);
    float*   p3     = (float*)(wsb + 256);
    float*   p2     = (float*)(wsb + 87183616u);
    float*   pooled = (float*)(wsb + 87183616u);
    unsigned short* s2p3 = (unsigned short*)(wsb + 171069696u);
    unsigned short* wt2b = (unsigned short*)(wsb + 216330496u);
    unsigned short* wt3b = (unsigned short*)(wsb + 216772864u);

    float alpha, beta;
    { uint32_t ab = 0x3F7383C6u; memcpy(&alpha, &ab, 4); }  // e^-0.05f
    { uint32_t bb = 0x3F519857u; memcpy(&beta,  &bb, 4); }  // e^-0.2f

    zpad1v<<<40, 256, 0, stream>>>((uint32_t*)s1p2);
    zpad3v<<<40, 256, 0, stream>>>((uint32_t*)s2p3);
    wtrans2c<<<288, 256, 0, stream>>>(w2, wt2b);
    wtrans3c<<<1152, 256, 0, stream>>>(w3, wt3b);
    conv1_lif<<<dim3(16, 128, 4), 256, 0, stream>>>(x, w1, b1, s1p2, alpha, beta);
    // L2 conv MFMA: grid (64 rows, 2 cobi, 40 frames), 256-thr, no LDS
    conv2_mfma<<<dim3(64, 2, 40), 256, 0, stream>>>(s1p2, wt2b, p2);
    lif_s2_t<<<dim3(512, 1, 4), 256, 0, stream>>>(p2, b2, s2p3, alpha, beta);
    // L3 conv MFMA: grid (16 row-pairs, 4 cobi, 40 frames), 256-thr, no LDS
    conv3_mfma3<<<dim3(16, 4, 40), 256, 0, stream>>>(s2p3, wt3b, p3);
    lif_mean1<<<dim3(1, 256, 4), 256, 0, stream>>>(p3, b3, pooled, alpha, beta);
    det_conv<<<dim3(16, 4, 4), 256, 0, stream>>>(pooled, wd, bd, out);
}

// Round 16
// 297.951 us; speedup vs baseline: 1.3857x; 1.3857x over previous
//
#include <hip/hip_runtime.h>
#include <stdint.h>
#include <string.h>
#include <cmath>

// SpikingYOLO round 34: REVERT to R31 (302.7us bank) after R33's barrier-free
// experiment regressed (130us conv2 — removing LDS reintroduced 4x A-frag
// duplication -> load-request-bound again). Conv engines are back to the
// proven R24/R31 structure BYTE-FOR-BYTE. Only change vs R31: zpad1v+zpad3v
// merged into one dispatch and wtrans2c+wtrans3c merged into one dispatch
// (disjoint index ranges, bodies verbatim) -> 8 launches instead of 10.
// absmax must equal 0.006835938.

#define BB 4
#define TT 10

typedef short bf16x8 __attribute__((ext_vector_type(8)));
typedef float f32x4  __attribute__((ext_vector_type(4)));

#define MFMA16(a, b, c) __builtin_amdgcn_mfma_f32_16x16x32_bf16((a), (b), (c), 0, 0, 0)

// s1p2: [40][129 rows][parity 2][cih 2][col2 66][cil 32] bf16
//   row stride 8448 elems, parity 4224, cih 2112; plane 1,089,792 elems.
// s2p3: [40][65][parity 2][cih 4][col2 34][cil 32] bf16
//   row stride 8704 elems, parity 4352, cih 1088; plane 565,760 elems.

// ---------------- zero pads of BOTH spike planes in one dispatch.
// blocks 0..39: s1p2 plane; blocks 40..79: s2p3 plane. Bodies verbatim.
__global__ __launch_bounds__(256) void zpad_all(
    uint32_t* __restrict__ b1v, uint32_t* __restrict__ b3v)
{
    if (blockIdx.x < 40) {
        uint32_t* p = b1v + (size_t)blockIdx.x * 544896u;
        for (int i = threadIdx.x; i < 8320; i += 256) {
            if (i < 4224) p[i] = 0u;
            else {
                int j = i - 4224;
                int row = 1 + (j >> 5), cih = (j >> 4) & 1, e = j & 15;
                p[row * 4224 + 2112 + cih * 1056 + e] = 0u;
            }
        }
    } else {
        uint32_t* p = b3v + (size_t)(blockIdx.x - 40) * 282880u;
        for (int i = threadIdx.x; i < 8448; i += 256) {
            if (i < 4352) p[i] = 0u;
            else {
                int j = i - 4352;
                int row = 1 + (j >> 6), cih = (j >> 4) & 3, e = j & 15;
                p[row * 4352 + 2176 + cih * 544 + e] = 0u;
            }
        }
    }
}

// ---------------------------------------------------------------- conv1+LIF
// Byte-identical to R31 (LDS-coalesced spike drain).
__global__ __launch_bounds__(256) void conv1_lif(
    const float* __restrict__ x,    // [4,2,128,128,10]
    const float* __restrict__ w1,   // [64,2,3,3]
    const float* __restrict__ b1,   // [64]
    unsigned short* __restrict__ s1p2,
    float alpha, float beta)
{
    __shared__ float xs[2][3][10][10];   // [ci][kh][wi][t]
    __shared__ float wsh[18][64];        // [tap][co]
    __shared__ uint32_t spk[40][68];
    const int tid = threadIdx.x;
    const int b = blockIdx.z, h = blockIdx.y, w0 = blockIdx.x * 8;

    for (int i = tid; i < 1152; i += 256) {
        int co = i & 63, tap = i >> 6;
        wsh[tap][co] = w1[co * 18 + tap];
    }
    for (int i = tid; i < 600; i += 256) {
        int t = i % 10; int rest = i / 10;
        int wi = rest % 10; rest /= 10;
        int kh = rest % 3; int ci = rest / 3;
        int hh = h - 1 + kh, ww = w0 - 1 + wi;
        float v = 0.f;
        if (hh >= 0 && hh < 128 && ww >= 0 && ww < 128)
            v = x[(((b * 2 + ci) * 128 + hh) * 128 + ww) * 10 + t];
        xs[ci][kh][wi][t] = v;
    }
    __syncthreads();

    const int px  = tid & 7;
    const int cog = (tid >> 3) * 2;
    float acc[2][10];
#pragma unroll
    for (int c = 0; c < 2; ++c)
#pragma unroll
        for (int t = 0; t < 10; ++t) acc[c][t] = 0.f;

#pragma unroll
    for (int tap = 0; tap < 18; ++tap) {
        const int ci = tap / 9, kh = (tap % 9) / 3, kw = tap % 3;
        float2 wv = *(const float2*)&wsh[tap][cog];
#pragma unroll
        for (int t = 0; t < 10; ++t) {
            float xv = xs[ci][kh][px + kw][t];
            acc[0][t] = __fmaf_rn(wv.x, xv, acc[0][t]);
            acc[1][t] = __fmaf_rn(wv.y, xv, acc[1][t]);
        }
    }
    const int pr    = px & 1;
    const int col2l = px >> 1;
    const int comb0 = pr * 2 + (cog >> 5);
    const int ipos  = col2l * 16 + ((cog & 31) >> 1);
    const float bv0 = b1[cog], bv1 = b1[cog + 1];
    float syn0 = 0.f, mem0 = 0.f, syn1 = 0.f, mem1 = 0.f;
#pragma unroll
    for (int t = 0; t < 10; ++t) {
        float cur0 = __fadd_rn(acc[0][t], bv0);
        syn0 = __fadd_rn(__fmul_rn(beta, syn0), cur0);
        mem0 = __fadd_rn(__fmul_rn(alpha, mem0), syn0);
        bool s0 = (mem0 >= 1.0f);
        mem0 = __fsub_rn(mem0, s0 ? 1.0f : 0.0f);
        float cur1 = __fadd_rn(acc[1][t], bv1);
        syn1 = __fadd_rn(__fmul_rn(beta, syn1), cur1);
        mem1 = __fadd_rn(__fmul_rn(alpha, mem1), syn1);
        bool s1 = (mem1 >= 1.0f);
        mem1 = __fsub_rn(mem1, s1 ? 1.0f : 0.0f);
        spk[t * 4 + comb0][ipos] =
            (s0 ? 0x3F80u : 0u) | ((s1 ? 0x3F80u : 0u) << 16);
    }
    __syncthreads();

    uint32_t* sg = (uint32_t*)s1p2;
    const int e = tid & 63;
#pragma unroll
    for (int k = 0; k < 10; ++k) {
        const int combo = k * 4 + (tid >> 6);       // 0..39
        const int t  = combo >> 2;
        const int pp = (combo >> 1) & 1;
        const int ch = combo & 1;
        const uint32_t ga = (uint32_t)(t * BB + b) * 544896u
            + ((uint32_t)((h + 1) * 8448 + pp * 4224 + ch * 2112
                          + ((w0 >> 1) + pp) * 32) >> 1) + e;
        sg[ga] = spk[combo][e];
    }
}

// --------- w2 AND w3 3-term bf16 splits in one dispatch (bodies verbatim).
// i < 73728: w2 path; else w3 path with i' = i - 73728.
__global__ __launch_bounds__(256) void wtrans_all(
    const float* __restrict__ w2, unsigned short* __restrict__ wtb2,
    const float* __restrict__ w3, unsigned short* __restrict__ wtb3)
{
    int i = blockIdx.x * 256 + threadIdx.x;
    if (i < 73728) {                         // 128*64*9
        int co  = i / 576;
        int rem = i - co * 576;
        int ci  = rem / 9;
        int tap = rem - ci * 9;
        float w = w2[i];                     // [co][ci][kh][kw]
        uint32_t uw  = __float_as_uint(w);
        uint32_t h16 = (uw + 0x7FFFu + ((uw >> 16) & 1u)) >> 16;   // RNE bf16
        float hf = __uint_as_float(h16 << 16);
        float r1 = w - hf;
        uint32_t ur1 = __float_as_uint(r1);
        uint32_t m16 = (ur1 + 0x7FFFu + ((ur1 >> 16) & 1u)) >> 16;
        float mf = __uint_as_float(m16 << 16);
        float r2 = r1 - mf;
        uint32_t ur2 = __float_as_uint(r2);
        uint32_t l16 = (ur2 + 0x7FFFu + ((ur2 >> 16) & 1u)) >> 16;

        int cobi = co >> 6, coL = co & 63;
        int wid = coL >> 4, l15 = coL & 15;
        int c = ci >> 5, r5 = ci & 31;
        int g = r5 >> 3, e = r5 & 7;
        size_t base = (size_t)(cobi * 27 + tap * 3) * 4096
                    + (size_t)(((wid * 2 + c) * 64 + (g * 16 + l15)) * 8 + e);
        wtb2[base]        = (unsigned short)h16;
        wtb2[base + 4096] = (unsigned short)m16;
        wtb2[base + 8192] = (unsigned short)l16;
    } else {
        int i3 = i - 73728;
        if (i3 >= 294912) return;            // 256*128*9
        int co  = i3 / 1152;
        int rem = i3 - co * 1152;
        int ci  = rem / 9;
        int tap = rem - ci * 9;
        float w = w3[i3];                    // [co][ci][kh][kw]
        uint32_t uw  = __float_as_uint(w);
        uint32_t h16 = (uw + 0x7FFFu + ((uw >> 16) & 1u)) >> 16;
        float hf = __uint_as_float(h16 << 16);
        float r1 = w - hf;
        uint32_t ur1 = __float_as_uint(r1);
        uint32_t m16 = (ur1 + 0x7FFFu + ((ur1 >> 16) & 1u)) >> 16;
        float mf = __uint_as_float(m16 << 16);
        float r2 = r1 - mf;
        uint32_t ur2 = __float_as_uint(r2);
        uint32_t l16 = (ur2 + 0x7FFFu + ((ur2 >> 16) & 1u)) >> 16;

        int cobi = co >> 6, coL = co & 63;
        int wq = coL >> 4, l15 = coL & 15;
        int cc = ci >> 5, r5 = ci & 31;
        int g = r5 >> 3, e = r5 & 7;
        size_t base = (size_t)(cobi * 27 + tap * 3) * 8192
                    + (size_t)(((wq * 4 + cc) * 64 + (g * 16 + l15)) * 8 + e);
        wtb3[base]         = (unsigned short)h16;
        wtb3[base + 8192]  = (unsigned short)m16;
        wtb3[base + 16384] = (unsigned short)l16;
    }
}

#define VMCNT(n) do { __builtin_amdgcn_sched_barrier(0); \
    asm volatile("s_waitcnt vmcnt(" #n ")" ::: "memory"); \
    __builtin_amdgcn_sched_barrier(0); } while (0)
#define SB() __builtin_amdgcn_sched_barrier(0)
#define BARR() do { __builtin_amdgcn_sched_barrier(0); \
    __builtin_amdgcn_s_barrier(); \
    __builtin_amdgcn_sched_barrier(0); } while (0)
#define PRIO1() __builtin_amdgcn_s_setprio(1)
#define PRIO0() __builtin_amdgcn_s_setprio(0)

// ------------------- L2 conv via MFMA. Byte-identical to R31 (R24 engine):
// 8-wave block, 64 px (1 row) x 128 co; ring-3 LDS A-stage (1 frag/wave),
// 6 B reg-loads dbuf, VMCNT(7), 1 barrier/phase, 8 ds_read + 24 MFMA.
__global__ __launch_bounds__(512) void conv2_mfma(
    const unsigned short* __restrict__ s1p2,
    const unsigned short* __restrict__ wtb,   // [2][27][4096]
    float* __restrict__ p2)                   // [40][4096][128]
{
    __shared__ alignas(16) unsigned short Bs[3][4096];   // ring-3 x 8KB
    const int tid  = threadIdx.x;
    const int lane = tid & 63, w = tid >> 6;
    const int r = lane & 15, g = lane >> 4;
    const int f = blockIdx.z;
    const int hb = blockIdx.x;                 // output row 0..63

    const unsigned short* fb = s1p2 + (uint32_t)f * 1089792u;
    const unsigned short* wB = wtb + (uint32_t)(w >> 2) * (27u * 4096u)
                             + (uint32_t)(w & 3) * 1024u + (uint32_t)lane * 8u;
    const uint32_t lfo = (uint32_t)(r * 32 + g * 8);   // in-frag lane offset

    f32x4 acc[4];
#pragma unroll
    for (int mt = 0; mt < 4; ++mt) acc[mt] = (f32x4){0.f, 0.f, 0.f, 0.f};
    bf16x8 bA[6], bB[6];

#define STAGE2(tap_, slot_) do { \
    const int kh_ = (tap_) / 3, kw_ = (tap_) % 3; \
    const int p_ = (kw_ == 1) ? 0 : 1; \
    const int cf_ = (kw_ == 2) ? 1 : 0; \
    const int mt_ = w >> 1, c_ = w & 1; \
    const unsigned short* src_ = fb + (uint32_t)(2 * hb + kh_) * 8448u \
        + (uint32_t)p_ * 4224u + (uint32_t)c_ * 2112u \
        + (uint32_t)(mt_ * 16 + cf_) * 32u + lfo; \
    __builtin_amdgcn_global_load_lds( \
        (const __attribute__((address_space(1))) unsigned int*)(const void*)src_, \
        (__attribute__((address_space(3))) unsigned int*)(void*)(&Bs[slot_][w * 512]), \
        16, 0, 0); \
} while (0)

#define LOADB2(tap_, DST) do { _Pragma("unroll") \
    for (int t_ = 0; t_ < 3; ++t_) { _Pragma("unroll") \
        for (int c_ = 0; c_ < 2; ++c_) \
            DST[t_ * 2 + c_] = *(const bf16x8*)(wB + (uint32_t)((tap_) * 3 + t_) * 4096u + c_ * 512u); \
    } } while (0)

#define COMP2(slot_, BU) do { \
    bf16x8 af_[8]; \
    _Pragma("unroll") \
    for (int q_ = 0; q_ < 8; ++q_) \
        af_[q_] = *(const bf16x8*)&Bs[slot_][q_ * 512 + lane * 8]; \
    _Pragma("unroll") \
    for (int t_ = 0; t_ < 3; ++t_) { _Pragma("unroll") \
        for (int c_ = 0; c_ < 2; ++c_) { \
            bf16x8 b_ = BU[t_ * 2 + c_]; \
            acc[0] = MFMA16(b_, af_[0 + c_], acc[0]); \
            acc[1] = MFMA16(b_, af_[2 + c_], acc[1]); \
            acc[2] = MFMA16(b_, af_[4 + c_], acc[2]); \
            acc[3] = MFMA16(b_, af_[6 + c_], acc[3]); \
        } } } while (0)

#define PH2(tap_, snxt_, scur_, BU, BN) do { \
    SB(); STAGE2((tap_) + 1, snxt_); LOADB2((tap_) + 1, BN); SB(); \
    VMCNT(7); BARR(); \
    PRIO1(); COMP2(scur_, BU); PRIO0(); SB(); \
} while (0)

    STAGE2(0, 0); LOADB2(0, bA);
    PH2(0, 1, 0, bA, bB); PH2(1, 2, 1, bB, bA); PH2(2, 0, 2, bA, bB);
    PH2(3, 1, 0, bB, bA); PH2(4, 2, 1, bA, bB); PH2(5, 0, 2, bB, bA);
    PH2(6, 1, 0, bA, bB); PH2(7, 2, 1, bB, bA);
    // tap 8 tail (slot 2, bA)
    SB(); VMCNT(0); BARR();
    PRIO1(); COMP2(2, bA); PRIO0();

#pragma unroll
    for (int mt = 0; mt < 4; ++mt)
        *(f32x4*)&p2[((uint32_t)f * 4096u + hb * 64 + mt * 16 + r) * 128u
                     + w * 16 + g * 4] = acc[mt];
#undef STAGE2
#undef LOADB2
#undef COMP2
#undef PH2
}

// ---------------------- LIF layer 2: MFMA partial -> bf16 spikes (s2p3).
// Byte-identical to R31.
__global__ __launch_bounds__(256) void lif_s2_t(
    const float* __restrict__ pa, const float* __restrict__ bias,
    unsigned short* __restrict__ s2p3, float alpha, float beta)
{
    const int tid = threadIdx.x;
    const int b   = blockIdx.z;
    const int px  = blockIdx.x * 8 + (tid >> 5);
    const int co0 = (tid & 31) * 4;
    const int h = px >> 6, w = px & 63;
    float4 bv = *(const float4*)&bias[co0];
    const float bva[4] = {bv.x, bv.y, bv.z, bv.w};
    float syn[4] = {0.f,0.f,0.f,0.f}, mem[4] = {0.f,0.f,0.f,0.f};
    const int pr = w & 1;
    const int col2 = (w + pr) >> 1;
    unsigned short* sp = s2p3 + (uint32_t)(h + 1) * 8704u + pr * 4352u
                       + (co0 >> 5) * 1088u + col2 * 32u + (co0 & 31);
    for (int t = 0; t < TT; ++t) {
        const int f = t * BB + b;
        const uint32_t idx = ((uint32_t)f * 4096u + px) * 128u + co0;
        float4 A = *(const float4*)&pa[idx];
        const float va[4] = {A.x, A.y, A.z, A.w};
        uint32_t pk[2] = {0u, 0u};
#pragma unroll
        for (int j = 0; j < 4; ++j) {
            float c = __fadd_rn(va[j], bva[j]);
            syn[j] = __fadd_rn(__fmul_rn(beta, syn[j]), c);
            mem[j] = __fadd_rn(__fmul_rn(alpha, mem[j]), syn[j]);
            bool sc = (mem[j] >= 1.0f);
            mem[j] = __fsub_rn(mem[j], sc ? 1.0f : 0.0f);
            pk[j >> 1] |= (sc ? 0x3F80u : 0u) << ((j & 1) * 16);
        }
        *(uint2*)(sp + (uint32_t)f * 565760u) = make_uint2(pk[0], pk[1]);
    }
}

// ------------------- L3 conv via MFMA. Byte-identical to R31:
// 8-wave block, 64 px (2 rows) x 128 co; 18 half-tap phases; per phase
// 1 stage + 6 B loads, VMCNT(7), barrier, 8 ds_read, 24 MFMA.
__global__ __launch_bounds__(512) void conv3_mfma3(
    const unsigned short* __restrict__ s2p3,
    const unsigned short* __restrict__ wtb,   // [4][27][8192]
    float* __restrict__ p3)                   // [40][256][32][32]
{
    __shared__ alignas(16) unsigned short Bs[3][4096];   // ring-3 x 8KB
    const int tid  = threadIdx.x;
    const int lane = tid & 63, w = tid >> 6;
    const int r = lane & 15, g = lane >> 4;
    const int f = blockIdx.z, cb2 = blockIdx.y;
    const int h0 = blockIdx.x * 2;

    const unsigned short* fb = s2p3 + (uint32_t)f * 565760u;
    const unsigned short* wB = wtb + (uint32_t)(cb2 * 2 + (w >> 2)) * (27u * 8192u)
                             + (uint32_t)(w & 3) * 2048u + (uint32_t)lane * 8u;
    const uint32_t lfo = (uint32_t)(r * 32 + g * 8);

    f32x4 acc[4];
#pragma unroll
    for (int mt = 0; mt < 4; ++mt) acc[mt] = (f32x4){0.f, 0.f, 0.f, 0.f};
    bf16x8 bA[6], bB[6];

#define STAGE3(tap_, half_, slot_) do { \
    const int kh_ = (tap_) / 3, kw_ = (tap_) % 3; \
    const int p_ = (kw_ == 1) ? 0 : 1; \
    const int cf_ = (kw_ == 2) ? 1 : 0; \
    const int mt_ = w >> 1, j_ = w & 1; \
    const unsigned short* src_ = fb \
        + (uint32_t)(2 * (h0 + (mt_ >> 1)) + kh_) * 8704u \
        + (uint32_t)p_ * 4352u + (uint32_t)((half_) * 2 + j_) * 1088u \
        + (uint32_t)((mt_ & 1) * 16 + cf_) * 32u + lfo; \
    __builtin_amdgcn_global_load_lds( \
        (const __attribute__((address_space(1))) unsigned int*)(const void*)src_, \
        (__attribute__((address_space(3))) unsigned int*)(void*)(&Bs[slot_][w * 512]), \
        16, 0, 0); \
} while (0)

#define LOADB3(tap_, half_, DST) do { _Pragma("unroll") \
    for (int t_ = 0; t_ < 3; ++t_) { _Pragma("unroll") \
        for (int j_ = 0; j_ < 2; ++j_) \
            DST[t_ * 2 + j_] = *(const bf16x8*)(wB + (uint32_t)((tap_) * 3 + t_) * 8192u \
                + (uint32_t)((half_) * 2 + j_) * 512u); \
    } } while (0)

#define COMP3(slot_, BU) do { \
    bf16x8 af_[8]; \
    _Pragma("unroll") \
    for (int q_ = 0; q_ < 8; ++q_) \
        af_[q_] = *(const bf16x8*)&Bs[slot_][q_ * 512 + lane * 8]; \
    _Pragma("unroll") \
    for (int t_ = 0; t_ < 3; ++t_) { _Pragma("unroll") \
        for (int j_ = 0; j_ < 2; ++j_) { \
            bf16x8 b_ = BU[t_ * 2 + j_]; \
            acc[0] = MFMA16(af_[0 + j_], b_, acc[0]); \
            acc[1] = MFMA16(af_[2 + j_], b_, acc[1]); \
            acc[2] = MFMA16(af_[4 + j_], b_, acc[2]); \
            acc[3] = MFMA16(af_[6 + j_], b_, acc[3]); \
        } } } while (0)

#define PH3(ntap_, nhalf_, snxt_, scur_, BU, BN) do { \
    SB(); STAGE3(ntap_, nhalf_, snxt_); LOADB3(ntap_, nhalf_, BN); SB(); \
    VMCNT(7); BARR(); \
    PRIO1(); COMP3(scur_, BU); PRIO0(); SB(); \
} while (0)

    STAGE3(0, 0, 0); LOADB3(0, 0, bA);
    PH3(0, 1, 1, 0, bA, bB); PH3(1, 0, 2, 1, bB, bA); PH3(1, 1, 0, 2, bA, bB);
    PH3(2, 0, 1, 0, bB, bA); PH3(2, 1, 2, 1, bA, bB); PH3(3, 0, 0, 2, bB, bA);
    PH3(3, 1, 1, 0, bA, bB); PH3(4, 0, 2, 1, bB, bA); PH3(4, 1, 0, 2, bA, bB);
    PH3(5, 0, 1, 0, bB, bA); PH3(5, 1, 2, 1, bA, bB); PH3(6, 0, 0, 2, bB, bA);
    PH3(6, 1, 1, 0, bA, bB); PH3(7, 0, 2, 1, bB, bA); PH3(7, 1, 0, 2, bA, bB);
    PH3(8, 0, 1, 0, bB, bA); PH3(8, 1, 2, 1, bA, bB);
    // phase 17 tail (tap 8, half 1): slot 2, bB
    SB(); VMCNT(0); BARR();
    PRIO1(); COMP3(2, bB); PRIO0();

#pragma unroll
    for (int mt = 0; mt < 4; ++mt) {
        const int hh = h0 + (mt >> 1);
        const int wc = (mt & 1) * 16 + g * 4;
        *(f32x4*)&p3[((uint32_t)(f * 256 + cb2 * 128 + w * 16 + r) * 32u + hh) * 32u + wc] = acc[mt];
    }
#undef STAGE3
#undef LOADB3
#undef COMP3
#undef PH3
}

// ---------------------- LIF + time-mean from the single conv3 buffer
__global__ __launch_bounds__(256) void lif_mean1(
    const float* __restrict__ p3, const float* __restrict__ bias,
    float* __restrict__ pooled, float alpha, float beta)
{
    const int px = (blockIdx.x * 256 + threadIdx.x) * 4;
    const int co = blockIdx.y;
    const int b  = blockIdx.z;
    const float bv = bias[co];
    float syn[4] = {0.f,0.f,0.f,0.f}, mem[4] = {0.f,0.f,0.f,0.f};
    float sum[4] = {0.f,0.f,0.f,0.f};
    for (int t = 0; t < TT; ++t) {
        const int idx = ((t * BB + b) * 256 + co) * 1024 + px;
        float4 a = *(const float4*)&p3[idx];
        const float va[4] = {a.x, a.y, a.z, a.w};
#pragma unroll
        for (int j = 0; j < 4; ++j) {
            float cu = __fadd_rn(va[j], bv);
            syn[j] = __fadd_rn(__fmul_rn(beta, syn[j]), cu);
            mem[j] = __fadd_rn(__fmul_rn(alpha, mem[j]), syn[j]);
            bool sc = (mem[j] >= 1.0f);
            float sp = sc ? 1.0f : 0.0f;
            mem[j] = __fsub_rn(mem[j], sp);
            sum[j] = __fadd_rn(sum[j], sp);
        }
    }
    *(float4*)&pooled[(b * 256 + co) * 1024 + px] =
        make_float4(sum[0] / 10.0f, sum[1] / 10.0f, sum[2] / 10.0f, sum[3] / 10.0f);
}

// ------------------------------------------------------------------ det 1x1
__global__ __launch_bounds__(256) void det_conv(
    const float* __restrict__ pooled, // [4,256,1024]
    const float* __restrict__ wd,     // [255,256]
    const float* __restrict__ bd,     // [255]
    float* __restrict__ out)          // [4,255,1024]
{
    __shared__ float wtl[16][64];
    __shared__ float ps[16][64];
    const int tid = threadIdx.x;
    const int b = blockIdx.z;
    const int o_base = blockIdx.y * 64;
    const int px_base = blockIdx.x * 64;
    const int o_off = (tid >> 4) * 4;
    const int px_off = (tid & 15) * 4;
    float acc[4][4];
#pragma unroll
    for (int c = 0; c < 4; ++c) {
        int o = o_base + o_off + c;
        float bv = (o < 255) ? bd[o] : 0.f;
#pragma unroll
        for (int j = 0; j < 4; ++j) acc[c][j] = bv;
    }
    for (int cc = 0; cc < 16; ++cc) {
        for (int k = tid; k < 1024; k += 256) {
            int o = k & 63, ci = k >> 6;
            wtl[ci][o] = (o_base + o < 255) ? wd[(o_base + o) * 256 + cc * 16 + ci] : 0.f;
            ps[ci][o] = pooled[(b * 256 + cc * 16 + ci) * 1024 + px_base + o];
        }
        __syncthreads();
#pragma unroll
        for (int ci = 0; ci < 16; ++ci) {
            float4 wv = *(const float4*)&wtl[ci][o_off];
            float4 sv = *(const float4*)&ps[ci][px_off];
            acc[0][0] += wv.x * sv.x; acc[0][1] += wv.x * sv.y;
            acc[0][2] += wv.x * sv.z; acc[0][3] += wv.x * sv.w;
            acc[1][0] += wv.y * sv.x; acc[1][1] += wv.y * sv.y;
            acc[1][2] += wv.y * sv.z; acc[1][3] += wv.y * sv.w;
            acc[2][0] += wv.z * sv.x; acc[2][1] += wv.z * sv.y;
            acc[2][2] += wv.z * sv.z; acc[2][3] += wv.z * sv.w;
            acc[3][0] += wv.w * sv.x; acc[3][1] += wv.w * sv.y;
            acc[3][2] += wv.w * sv.z; acc[3][3] += wv.w * sv.w;
        }
        __syncthreads();
    }
#pragma unroll
    for (int c = 0; c < 4; ++c) {
        int o = o_base + o_off + c;
        if (o < 255)
            *(float4*)&out[(b * 255 + o) * 1024 + px_base + px_off] =
                make_float4(acc[c][0], acc[c][1], acc[c][2], acc[c][3]);
    }
}

extern "C" void kernel_launch(void* const* d_in, const int* in_sizes, int n_in,
                              void* d_out, int out_size, void* d_ws, size_t ws_size,
                              hipStream_t stream) {
    const float* x  = (const float*)d_in[0];
    const float* w1 = (const float*)d_in[1];
    const float* b1 = (const float*)d_in[2];
    const float* w2 = (const float*)d_in[3];
    const float* b2 = (const float*)d_in[4];
    const float* w3 = (const float*)d_in[5];
    const float* b3 = (const float*)d_in[6];
    const float* wd = (const float*)d_in[7];
    const float* bd = (const float*)d_in[8];
    float* out = (float*)d_out;

    // ws layout with aliasing (lifetimes; ~218.5 MB), identical to R29/R31:
    //   s1p2 u16 [40][1,089,792]   @ 256          (87,183,360)  conv1 -> conv2
    //   p3   f32 [40*256*1024]     @ 256          (41,943,040)  conv3 -> lif_mean1 (overlays s1p2)
    //   p2   f32 [40][4096][128]   @ 87,183,616   (83,886,080)  conv2 -> lif_s2_t
    //   pooled f32                 @ 87,183,616   (4,194,304)   lif_mean1 -> det (overlays p2)
    //   s2p3 u16 [40][565,760]     @ 171,069,696  (45,260,800)  lif_s2_t -> conv3
    //   wt2b u16 [2][27][4096]     @ 216,330,496  (442,368)
    //   wt3b u16 [4][27][8192]     @ 216,772,864  (1,769,472)   end 218,542,336
    uint8_t* wsb = (uint8_t*)d_ws;
    unsigned short* s1p2 = (unsigned short*)(wsb + 256);
    float*   p3     = (float*)(wsb + 256);
    float*   p2     = (float*)(wsb + 87183616u);
    float*   pooled = (float*)(wsb + 87183616u);
    unsigned short* s2p3 = (unsigned short*)(wsb + 171069696u);
    unsigned short* wt2b = (unsigned short*)(wsb + 216330496u);
    unsigned short* wt3b = (unsigned short*)(wsb + 216772864u);

    float alpha, beta;
    { uint32_t ab = 0x3F7383C6u; memcpy(&alpha, &ab, 4); }  // e^-0.05f
    { uint32_t bb = 0x3F519857u; memcpy(&beta,  &bb, 4); }  // e^-0.2f

    zpad_all<<<80, 256, 0, stream>>>((uint32_t*)s1p2, (uint32_t*)s2p3);
    wtrans_all<<<1440, 256, 0, stream>>>(w2, wt2b, w3, wt3b);
    conv1_lif<<<dim3(16, 128, 4), 256, 0, stream>>>(x, w1, b1, s1p2, alpha, beta);
    // L2 conv MFMA: grid (64 rows, 1, 40 frames), 512-thread blocks
    conv2_mfma<<<dim3(64, 1, 40), 512, 0, stream>>>(s1p2, wt2b, p2);
    lif_s2_t<<<dim3(512, 1, 4), 256, 0, stream>>>(p2, b2, s2p3, alpha, beta);
    // L3 conv MFMA: grid (16 row-pairs, 2 co-halves, 40 frames), 512 threads
    conv3_mfma3<<<dim3(16, 2, 40), 512, 0, stream>>>(s2p3, wt3b, p3);
    lif_mean1<<<dim3(1, 256, 4), 256, 0, stream>>>(p3, b3, pooled, alpha, beta);
    det_conv<<<dim3(16, 4, 4), 256, 0, stream>>>(pooled, wd, bd, out);
}